// Round 3
// baseline (331.186 us; speedup 1.0000x reference)
//
#include <hip/hip_runtime.h>
#include <hip/hip_bf16.h>

// Problem: x (16,512,512,3) fp32, NHWC. Output (16,3,512,512,3):
//   out[b][s][h][w][c] = avgpool_same_{k_s}(x)[b][h][w][c] - x[b][h][w][c]
// with k in {7,15,31}, exclude-padding averages (divide by valid count).
// Separable: horizontal window sums via row prefix sums (K1), then vertical
// incremental sliding sums (K2). counts = rowcount(h)*colcount(w).

#define HH 512
#define WW 512
#define CC 3
#define ROWF (WW * CC)          // 1536 floats per (b,h) row
#define NROWS (16 * HH)         // 8192 rows

// ---------------- K1: per-row inclusive prefix sums (per channel) -----------
// One 64-lane wave per (b,h) row. Each lane owns 24 consecutive floats
// (8 w-positions x 3 channels), loaded as 6 float4s (coalesced).
__global__ __launch_bounds__(256) void row_prefix_kernel(
    const float* __restrict__ x, float* __restrict__ P) {
  const int wave = threadIdx.x >> 6;
  const int lane = threadIdx.x & 63;
  const int row = blockIdx.x * 4 + wave;      // 0..8191
  const size_t base = (size_t)row * ROWF + (size_t)lane * 24;

  float v[24];
  const float4* s4 = reinterpret_cast<const float4*>(x + base);
#pragma unroll
  for (int i = 0; i < 6; ++i) {
    float4 t = s4[i];
    v[i * 4 + 0] = t.x; v[i * 4 + 1] = t.y;
    v[i * 4 + 2] = t.z; v[i * 4 + 3] = t.w;
  }

  // local inclusive prefix per channel over the lane's 8 w-positions
  float tot[3];
#pragma unroll
  for (int c = 0; c < 3; ++c) {
    float run = 0.f;
#pragma unroll
    for (int wl = 0; wl < 8; ++wl) { run += v[wl * 3 + c]; v[wl * 3 + c] = run; }
    tot[c] = run;
  }

  // wave-wide exclusive scan of lane totals (64-lane shfl_up scan)
#pragma unroll
  for (int c = 0; c < 3; ++c) {
    float t = tot[c];
#pragma unroll
    for (int d = 1; d < 64; d <<= 1) {
      float n = __shfl_up(t, d, 64);
      if (lane >= d) t += n;
    }
    float off = t - tot[c];     // exclusive offset for this lane
#pragma unroll
    for (int wl = 0; wl < 8; ++wl) v[wl * 3 + c] += off;
  }

  float4* d4 = reinterpret_cast<float4*>(P + base);
#pragma unroll
  for (int i = 0; i < 6; ++i)
    d4[i] = make_float4(v[i * 4 + 0], v[i * 4 + 1], v[i * 4 + 2], v[i * 4 + 3]);
}

// ---------------- K2: vertical incremental sweep ----------------------------
// Each thread owns one (w,c) and sweeps 64 consecutive h. Horizontal window
// sum of row hh for scale s: hsum = P[hh][hi_s] - mlo_s * P[hh][lo_s-1]
// (2 loads, L1-resident across the block). Vertical window kept as a running
// sum S[s], updated incrementally (+incoming row, -outgoing row).
__global__ __launch_bounds__(256) void window_dev_kernel(
    const float* __restrict__ x, const float* __restrict__ P,
    float* __restrict__ out) {
  const int RAD[3] = {3, 7, 15};

  const int flat = blockIdx.x * 256 + threadIdx.x;  // 0..1535 (w*3 + c)
  const int w = flat / 3;
  const int c = flat - w * 3;
  const int b = blockIdx.z;
  const int h0 = blockIdx.y * 64;

  const float* Pb = P + (size_t)b * HH * ROWF;
  const float* xb = x + (size_t)b * HH * ROWF;
  float* ob = out + (size_t)b * 3 * HH * ROWF;

  int ihi[3], ilo[3];
  float mlo[3], invcol[3];
#pragma unroll
  for (int s = 0; s < 3; ++s) {
    const int r = RAD[s];
    int lo = w - r; if (lo < 0) lo = 0;
    int hi = w + r; if (hi > WW - 1) hi = WW - 1;
    invcol[s] = __builtin_amdgcn_rcpf((float)(hi - lo + 1));
    ihi[s] = hi * 3 + c;
    ilo[s] = (lo > 0) ? ((lo - 1) * 3 + c) : c;
    mlo[s] = (lo > 0) ? 1.f : 0.f;
  }

  // prologue: S[s] = sum of hsum over rows [max(0,h0-r), min(511,h0+r)]
  float S[3];
#pragma unroll
  for (int s = 0; s < 3; ++s) {
    const int r = RAD[s];
    int r0 = h0 - r; if (r0 < 0) r0 = 0;
    int r1 = h0 + r; if (r1 > HH - 1) r1 = HH - 1;
    float acc = 0.f;
    for (int hh = r0; hh <= r1; ++hh) {
      const float* Pr = Pb + (size_t)hh * ROWF;
      acc += Pr[ihi[s]] - mlo[s] * Pr[ilo[s]];
    }
    S[s] = acc;
  }

  for (int h = h0; h < h0 + 64; ++h) {
    const float xv = xb[(size_t)h * ROWF + flat];
    // uniform per-h row-count reciprocals (scalar-unit friendly)
    float invrow[3];
#pragma unroll
    for (int s = 0; s < 3; ++s) {
      const int r = RAD[s];
      int rt = h + r; if (rt > HH - 1) rt = HH - 1;
      int rb = h - r; if (rb < 0) rb = 0;
      invrow[s] = __builtin_amdgcn_rcpf((float)(rt - rb + 1));
    }
#pragma unroll
    for (int s = 0; s < 3; ++s) {
      const int r = RAD[s];
      const float avg = S[s] * (invrow[s] * invcol[s]);
      ob[((size_t)s * HH + h) * ROWF + flat] = avg - xv;

      // advance S[s] from window(h) to window(h+1)
      const int add = h + 1 + r;
      const int rem = h - r;
      float d = 0.f;
      if (add < HH) {
        const float* Pr = Pb + (size_t)add * ROWF;
        d += Pr[ihi[s]] - mlo[s] * Pr[ilo[s]];
      }
      if (rem >= 0) {
        const float* Pr = Pb + (size_t)rem * ROWF;
        d -= Pr[ihi[s]] - mlo[s] * Pr[ilo[s]];
      }
      S[s] += d;
    }
  }
}

extern "C" void kernel_launch(void* const* d_in, const int* in_sizes, int n_in,
                              void* d_out, int out_size, void* d_ws, size_t ws_size,
                              hipStream_t stream) {
  const float* x = (const float*)d_in[0];
  float* outp = (float*)d_out;
  float* P = (float*)d_ws;  // 16*512*512*3 floats = 50,331,648 bytes

  // K1: 8192 rows, 4 waves (4 rows) per 256-thread block
  row_prefix_kernel<<<NROWS / 4, 256, 0, stream>>>(x, P);

  // K2: grid = (w-chunks of 256 (w,c) slots, h-segments of 64, batch)
  dim3 grid(ROWF / 256, HH / 64, 16);
  window_dev_kernel<<<grid, 256, 0, stream>>>(x, P, outp);
}

// Round 4
// 253.027 us; speedup vs baseline: 1.3089x; 1.3089x over previous
//
#include <hip/hip_runtime.h>
#include <hip/hip_bf16.h>

// x (16,512,512,3) fp32 NHWC -> out (16,3,512,512,3):
//   out[b][s][h][w][c] = avgpool_same_{k_s}(x) - x,  k in {7,15,31},
// exclude-padding averages (count = rowcnt(h)*colcnt(w)).
//
// New path: 2D integral image.
//   K1  row prefix -> padded I rows (left pad = 0, right pad = row total)
//   K1b in-place vertical partial prefix per 32-row block + block totals T
//   K2  window = I[rt](chi-clo) - I[rb-1](chi-clo) (+ T fixup), no sweep.

#define HH 512
#define WW 512
#define ROWF 1536               // data floats per row (512*3)
#define NROWS (16 * HH)
#define PADL 48                 // 16 px * 3 c
#define PADR 48
#define RSTR (PADL + ROWF + PADR)  // 1632 floats
#define HBLK 32
#define NBLK (HH / HBLK)        // 16
#define NB 16

static const size_t I_FLOATS = (size_t)NB * HH * RSTR;     // 13,369,344
static const size_t T_FLOATS = (size_t)NB * NBLK * RSTR;   // 417,792

// ---------------- K1: row prefix into padded I --------------------------
__global__ __launch_bounds__(256) void row_prefix_pad(
    const float* __restrict__ x, float* __restrict__ I) {
  const int wave = threadIdx.x >> 6;
  const int lane = threadIdx.x & 63;
  const int row = blockIdx.x * 4 + wave;          // b*512 + h
  const float4* s4 = (const float4*)(x + (size_t)row * ROWF + lane * 24);

  float v[24];
#pragma unroll
  for (int i = 0; i < 6; ++i) {
    float4 t = s4[i];
    v[4*i] = t.x; v[4*i+1] = t.y; v[4*i+2] = t.z; v[4*i+3] = t.w;
  }
  float tot[3];
#pragma unroll
  for (int c = 0; c < 3; ++c) {
    float run = 0.f;
#pragma unroll
    for (int wl = 0; wl < 8; ++wl) { run += v[wl*3+c]; v[wl*3+c] = run; }
    tot[c] = run;
  }
  float rowtot[3];
#pragma unroll
  for (int c = 0; c < 3; ++c) {
    float t = tot[c];
#pragma unroll
    for (int d = 1; d < 64; d <<= 1) {
      float n = __shfl_up(t, d, 64);
      if (lane >= d) t += n;
    }
    float off = t - tot[c];
#pragma unroll
    for (int wl = 0; wl < 8; ++wl) v[wl*3+c] += off;
    rowtot[c] = __shfl(t, 63, 64);                // full-row channel total
  }

  float* dst = I + (size_t)row * RSTR;
  float4* d4 = (float4*)(dst + PADL + lane * 24);
#pragma unroll
  for (int i = 0; i < 6; ++i)
    d4[i] = make_float4(v[4*i], v[4*i+1], v[4*i+2], v[4*i+3]);

  if (lane < 12) {
    ((float4*)dst)[lane] = make_float4(0.f, 0.f, 0.f, 0.f);   // left pad
    float p[4];
#pragma unroll
    for (int j = 0; j < 4; ++j) p[j] = rowtot[(lane * 4 + j) % 3];
    ((float4*)(dst + PADL + ROWF))[lane] = make_float4(p[0], p[1], p[2], p[3]);
  }
}

// ---------------- K1b: vertical partial prefix (in place) + totals ------
__global__ __launch_bounds__(256) void col_partial_prefix(
    float* __restrict__ I, float* __restrict__ T) {
  const int j = blockIdx.x * 256 + threadIdx.x;   // f4-column, 0..407
  if (j >= RSTR / 4) return;
  const int blk = blockIdx.y, b = blockIdx.z;
  float4* base = (float4*)(I + ((size_t)b * HH + blk * HBLK) * RSTR) + j;
  const int st4 = RSTR / 4;

  float4 run = base[0];
#pragma unroll 4
  for (int i = 1; i < HBLK; ++i) {
    float4 nv = base[(size_t)i * st4];
    run.x += nv.x; run.y += nv.y; run.z += nv.z; run.w += nv.w;
    base[(size_t)i * st4] = run;
  }
  ((float4*)(T + ((size_t)b * NBLK + blk) * RSTR))[j] = run;
}

// ---------------- K2: per-(b,h) window deviations -----------------------
// Rp = row_start + PADL + f. chi loads: floats [f+3r .. f+3r+3] via two
// aligned float4 (3r-1 and 3r+3 are multiples of 4 for r in {3,7,15});
// clo load at -3r-3 is aligned.
template <bool SUB>
__device__ __forceinline__ void acc_hsum(const float* __restrict__ Rp,
                                         int r3, float4& a) {
  float4 L = *(const float4*)(Rp + r3 - 1);
  float4 H = *(const float4*)(Rp + r3 + 3);
  float4 C = *(const float4*)(Rp - r3 - 3);
  if (!SUB) {
    a.x += L.y - C.x; a.y += L.z - C.y; a.z += L.w - C.z; a.w += H.x - C.w;
  } else {
    a.x -= L.y - C.x; a.y -= L.z - C.y; a.z -= L.w - C.z; a.w -= H.x - C.w;
  }
}

__global__ __launch_bounds__(384) void win_dev_ii(
    const float* __restrict__ x, const float* __restrict__ I,
    const float* __restrict__ T, float* __restrict__ out) {
  const int h = blockIdx.x, b = blockIdx.y;
  const int f = threadIdx.x * 4;
  const float* Ib = I + (size_t)b * HH * RSTR;
  const float* Tb = T + (size_t)b * NBLK * RSTR;
  const float4 xv = *(const float4*)(x + ((size_t)b * HH + h) * ROWF + f);
  float* ob = out + ((size_t)b * 3 * HH + h) * ROWF + f;

  int wj[4];
#pragma unroll
  for (int j = 0; j < 4; ++j) wj[j] = (f + j) / 3;

  const int RADv[3] = {3, 7, 15};
#pragma unroll
  for (int s = 0; s < 3; ++s) {
    const int r = RADv[s], r3 = 3 * r;
    const int rt = min(h + r, HH - 1);
    const int rb = h - r;
    float4 hs = make_float4(0.f, 0.f, 0.f, 0.f);
    acc_hsum<false>(Ib + (size_t)rt * RSTR + PADL + f, r3, hs);
    if (rb >= 1) {
      acc_hsum<true>(Ib + (size_t)(rb - 1) * RSTR + PADL + f, r3, hs);
      const int bt = rt >> 5, bb = (rb - 1) >> 5;
      if (bt != bb)  // window spans one block boundary: add T[bb]
        acc_hsum<false>(Tb + (size_t)bb * RSTR + PADL + f, r3, hs);
    }
    const int rowcnt = rt - max(rb, 0) + 1;
    const float invrow = __builtin_amdgcn_rcpf((float)rowcnt);
    float hv[4] = {hs.x, hs.y, hs.z, hs.w};
    float xs[4] = {xv.x, xv.y, xv.z, xv.w};
    float rv[4];
#pragma unroll
    for (int j = 0; j < 4; ++j) {
      int cc = min(wj[j] + r, WW - 1) - max(wj[j] - r, 0) + 1;
      rv[j] = hv[j] * (invrow * __builtin_amdgcn_rcpf((float)cc)) - xs[j];
    }
    *(float4*)(ob + (size_t)s * HH * ROWF) =
        make_float4(rv[0], rv[1], rv[2], rv[3]);
  }
}

// ================= fallback path (round-3, proven passing) ==============
__global__ __launch_bounds__(256) void row_prefix_kernel(
    const float* __restrict__ x, float* __restrict__ P) {
  const int wave = threadIdx.x >> 6;
  const int lane = threadIdx.x & 63;
  const int row = blockIdx.x * 4 + wave;
  const size_t base = (size_t)row * ROWF + (size_t)lane * 24;
  float v[24];
  const float4* s4 = reinterpret_cast<const float4*>(x + base);
#pragma unroll
  for (int i = 0; i < 6; ++i) {
    float4 t = s4[i];
    v[i*4] = t.x; v[i*4+1] = t.y; v[i*4+2] = t.z; v[i*4+3] = t.w;
  }
  float tot[3];
#pragma unroll
  for (int c = 0; c < 3; ++c) {
    float run = 0.f;
#pragma unroll
    for (int wl = 0; wl < 8; ++wl) { run += v[wl*3+c]; v[wl*3+c] = run; }
    tot[c] = run;
  }
#pragma unroll
  for (int c = 0; c < 3; ++c) {
    float t = tot[c];
#pragma unroll
    for (int d = 1; d < 64; d <<= 1) {
      float n = __shfl_up(t, d, 64);
      if (lane >= d) t += n;
    }
    float off = t - tot[c];
#pragma unroll
    for (int wl = 0; wl < 8; ++wl) v[wl*3+c] += off;
  }
  float4* d4 = reinterpret_cast<float4*>(P + base);
#pragma unroll
  for (int i = 0; i < 6; ++i)
    d4[i] = make_float4(v[i*4], v[i*4+1], v[i*4+2], v[i*4+3]);
}

__global__ __launch_bounds__(256) void window_dev_kernel(
    const float* __restrict__ x, const float* __restrict__ P,
    float* __restrict__ out) {
  const int RAD[3] = {3, 7, 15};
  const int flat = blockIdx.x * 256 + threadIdx.x;
  const int w = flat / 3;
  const int c = flat - w * 3;
  const int b = blockIdx.z;
  const int h0 = blockIdx.y * 64;
  const float* Pb = P + (size_t)b * HH * ROWF;
  const float* xb = x + (size_t)b * HH * ROWF;
  float* ob = out + (size_t)b * 3 * HH * ROWF;
  int ihi[3], ilo[3];
  float mlo[3], invcol[3];
#pragma unroll
  for (int s = 0; s < 3; ++s) {
    const int r = RAD[s];
    int lo = w - r; if (lo < 0) lo = 0;
    int hi = w + r; if (hi > WW - 1) hi = WW - 1;
    invcol[s] = __builtin_amdgcn_rcpf((float)(hi - lo + 1));
    ihi[s] = hi * 3 + c;
    ilo[s] = (lo > 0) ? ((lo - 1) * 3 + c) : c;
    mlo[s] = (lo > 0) ? 1.f : 0.f;
  }
  float S[3];
#pragma unroll
  for (int s = 0; s < 3; ++s) {
    const int r = RAD[s];
    int r0 = h0 - r; if (r0 < 0) r0 = 0;
    int r1 = h0 + r; if (r1 > HH - 1) r1 = HH - 1;
    float acc = 0.f;
    for (int hh = r0; hh <= r1; ++hh) {
      const float* Pr = Pb + (size_t)hh * ROWF;
      acc += Pr[ihi[s]] - mlo[s] * Pr[ilo[s]];
    }
    S[s] = acc;
  }
  for (int h = h0; h < h0 + 64; ++h) {
    const float xvv = xb[(size_t)h * ROWF + flat];
    float invrow[3];
#pragma unroll
    for (int s = 0; s < 3; ++s) {
      const int r = RAD[s];
      int rt = h + r; if (rt > HH - 1) rt = HH - 1;
      int rbv = h - r; if (rbv < 0) rbv = 0;
      invrow[s] = __builtin_amdgcn_rcpf((float)(rt - rbv + 1));
    }
#pragma unroll
    for (int s = 0; s < 3; ++s) {
      const int r = RAD[s];
      const float avg = S[s] * (invrow[s] * invcol[s]);
      ob[((size_t)s * HH + h) * ROWF + flat] = avg - xvv;
      const int add = h + 1 + r;
      const int rem = h - r;
      float d = 0.f;
      if (add < HH) {
        const float* Pr = Pb + (size_t)add * ROWF;
        d += Pr[ihi[s]] - mlo[s] * Pr[ilo[s]];
      }
      if (rem >= 0) {
        const float* Pr = Pb + (size_t)rem * ROWF;
        d -= Pr[ihi[s]] - mlo[s] * Pr[ilo[s]];
      }
      S[s] += d;
    }
  }
}

// ========================================================================
extern "C" void kernel_launch(void* const* d_in, const int* in_sizes, int n_in,
                              void* d_out, int out_size, void* d_ws, size_t ws_size,
                              hipStream_t stream) {
  const float* x = (const float*)d_in[0];
  float* outp = (float*)d_out;
  const size_t need = (I_FLOATS + T_FLOATS) * sizeof(float);

  if (ws_size >= need) {
    float* I = (float*)d_ws;
    float* T = I + I_FLOATS;
    row_prefix_pad<<<NROWS / 4, 256, 0, stream>>>(x, I);
    dim3 g1b((RSTR / 4 + 255) / 256, NBLK, NB);   // (2,16,16)
    col_partial_prefix<<<g1b, 256, 0, stream>>>(I, T);
    dim3 g2(HH, NB);
    win_dev_ii<<<g2, 384, 0, stream>>>(x, I, T, outp);
  } else {
    float* P = (float*)d_ws;
    row_prefix_kernel<<<NROWS / 4, 256, 0, stream>>>(x, P);
    dim3 grid(ROWF / 256, HH / 64, 16);
    window_dev_kernel<<<grid, 256, 0, stream>>>(x, P, outp);
  }
}

// Round 5
// 235.016 us; speedup vs baseline: 1.4092x; 1.0766x over previous
//
#include <hip/hip_runtime.h>
#include <hip/hip_bf16.h>

// x (16,512,512,3) fp32 NHWC -> out (16,3,512,512,3):
//   out[b][s][h][w][c] = avgpool_same_{k_s}(x) - x,  k in {7,15,31},
// exclude-padding averages (count = rowcnt(h)*colcnt(w)).
//
// K1 (fused): row prefix + 32-row-block vertical prefix + block totals T,
//             single pass over HBM (re-read of just-written rows hits L2).
// K2: window = I[rt] - I[rb-1] + T fixup; XCD-banded h mapping for L2 reuse.

#define HH 512
#define WW 512
#define ROWF 1536               // data floats per row (512*3)
#define NROWS (16 * HH)
#define PADL 48                 // 16 px * 3 c
#define PADR 48
#define RSTR (PADL + ROWF + PADR)  // 1632 floats
#define HBLK 32
#define NBLK (HH / HBLK)        // 16
#define NB 16

static const size_t I_FLOATS = (size_t)NB * HH * RSTR;     // 13,369,344
static const size_t T_FLOATS = (size_t)NB * NBLK * RSTR;   // 417,792

// ---------------- K1: fused row prefix + vertical partial prefix --------
// 256 threads = 4 waves; block owns 32 rows of one image. Wave w handles
// rows [w*8, w*8+8): row scan (as before) + vertical running acc in regs,
// stores intra-wave vertical prefix. Cross-wave offsets via LDS; waves 1-3
// re-read their rows (L2-hot) and add offsets; wave 0 writes T.
__global__ __launch_bounds__(256) void fused_prefix(
    const float* __restrict__ x, float* __restrict__ I, float* __restrict__ T) {
  __shared__ float wtot[4][64][25];   // stride 25 -> bank-conflict-free
  const int wv = threadIdx.x >> 6;
  const int lane = threadIdx.x & 63;
  const int blk = blockIdx.x;         // 0..NBLK-1
  const int b = blockIdx.y;           // 0..NB-1
  const int row0 = b * HH + blk * HBLK + wv * 8;

  float acc[24];
#pragma unroll
  for (int j = 0; j < 24; ++j) acc[j] = 0.f;

  for (int rr = 0; rr < 8; ++rr) {
    const int row = row0 + rr;
    const float4* s4 = (const float4*)(x + (size_t)row * ROWF + lane * 24);
    float v[24];
#pragma unroll
    for (int i = 0; i < 6; ++i) {
      float4 t = s4[i];
      v[4*i] = t.x; v[4*i+1] = t.y; v[4*i+2] = t.z; v[4*i+3] = t.w;
    }
    // per-channel local prefix over the lane's 8 w-positions
    float tot[3];
#pragma unroll
    for (int c = 0; c < 3; ++c) {
      float run = 0.f;
#pragma unroll
      for (int wl = 0; wl < 8; ++wl) { run += v[wl*3+c]; v[wl*3+c] = run; }
      tot[c] = run;
    }
    // wave-wide exclusive scan of lane totals
#pragma unroll
    for (int c = 0; c < 3; ++c) {
      float t = tot[c];
#pragma unroll
      for (int d = 1; d < 64; d <<= 1) {
        float n = __shfl_up(t, d, 64);
        if (lane >= d) t += n;
      }
      float off = t - tot[c];
#pragma unroll
      for (int wl = 0; wl < 8; ++wl) v[wl*3+c] += off;
    }
    // vertical accumulate (intra-wave prefix) and store row
#pragma unroll
    for (int j = 0; j < 24; ++j) acc[j] += v[j];

    float rp0 = __shfl(acc[21], 63, 64);   // vertical-prefixed row totals
    float rp1 = __shfl(acc[22], 63, 64);
    float rp2 = __shfl(acc[23], 63, 64);

    float* dst = I + (size_t)row * RSTR;
    float4* d4 = (float4*)(dst + PADL + lane * 24);
#pragma unroll
    for (int i = 0; i < 6; ++i)
      d4[i] = make_float4(acc[4*i], acc[4*i+1], acc[4*i+2], acc[4*i+3]);
    if (lane < 12) {
      ((float4*)dst)[lane] = make_float4(0.f, 0.f, 0.f, 0.f);
      float rp[3] = {rp0, rp1, rp2};
      float p[4];
#pragma unroll
      for (int j = 0; j < 4; ++j) p[j] = rp[(lane * 4 + j) % 3];
      ((float4*)(dst + PADL + ROWF))[lane] = make_float4(p[0], p[1], p[2], p[3]);
    }
  }

#pragma unroll
  for (int j = 0; j < 24; ++j) wtot[wv][lane][j] = acc[j];
  __syncthreads();

  if (wv == 0) {
    // block totals -> T row (with pads)
    float tt[24];
#pragma unroll
    for (int j = 0; j < 24; ++j)
      tt[j] = wtot[0][lane][j] + wtot[1][lane][j] + wtot[2][lane][j] + wtot[3][lane][j];
    float* trow = T + ((size_t)b * NBLK + blk) * RSTR;
    float4* t4 = (float4*)(trow + PADL + lane * 24);
#pragma unroll
    for (int i = 0; i < 6; ++i)
      t4[i] = make_float4(tt[4*i], tt[4*i+1], tt[4*i+2], tt[4*i+3]);
    if (lane < 12) {
      ((float4*)trow)[lane] = make_float4(0.f, 0.f, 0.f, 0.f);
      float tp[3];
#pragma unroll
      for (int c = 0; c < 3; ++c)
        tp[c] = wtot[0][63][21+c] + wtot[1][63][21+c] +
                wtot[2][63][21+c] + wtot[3][63][21+c];
      float p[4];
#pragma unroll
      for (int j = 0; j < 4; ++j) p[j] = tp[(lane * 4 + j) % 3];
      ((float4*)(trow + PADL + ROWF))[lane] = make_float4(p[0], p[1], p[2], p[3]);
    }
  } else {
    float off[24];
#pragma unroll
    for (int j = 0; j < 24; ++j) {
      float o = wtot[0][lane][j];
      if (wv >= 2) o += wtot[1][lane][j];
      if (wv >= 3) o += wtot[2][lane][j];
      off[j] = o;
    }
    float offp[3];
#pragma unroll
    for (int c = 0; c < 3; ++c) {
      float o = wtot[0][63][21+c];
      if (wv >= 2) o += wtot[1][63][21+c];
      if (wv >= 3) o += wtot[2][63][21+c];
      offp[c] = o;
    }
    for (int rr = 0; rr < 8; ++rr) {
      float* dst = I + (size_t)(row0 + rr) * RSTR;
      float4* d4 = (float4*)(dst + PADL + lane * 24);
#pragma unroll
      for (int i = 0; i < 6; ++i) {
        float4 t = d4[i];
        t.x += off[4*i]; t.y += off[4*i+1]; t.z += off[4*i+2]; t.w += off[4*i+3];
        d4[i] = t;
      }
      if (lane < 12) {
        float4* rp = ((float4*)(dst + PADL + ROWF)) + lane;
        float4 t = *rp;
        t.x += offp[(lane*4+0)%3]; t.y += offp[(lane*4+1)%3];
        t.z += offp[(lane*4+2)%3]; t.w += offp[(lane*4+3)%3];
        *rp = t;
      }
    }
  }
}

// ---------------- K2: per-(b,h) window deviations -----------------------
template <bool SUB>
__device__ __forceinline__ void acc_hsum(const float* __restrict__ Rp,
                                         int r3, float4& a) {
  float4 L = *(const float4*)(Rp + r3 - 1);
  float4 H = *(const float4*)(Rp + r3 + 3);
  float4 C = *(const float4*)(Rp - r3 - 3);
  if (!SUB) {
    a.x += L.y - C.x; a.y += L.z - C.y; a.z += L.w - C.z; a.w += H.x - C.w;
  } else {
    a.x -= L.y - C.x; a.y -= L.z - C.y; a.z -= L.w - C.z; a.w -= H.x - C.w;
  }
}

__global__ __launch_bounds__(384) void win_dev_ii(
    const float* __restrict__ x, const float* __restrict__ I,
    const float* __restrict__ T, float* __restrict__ out) {
  const int bx = blockIdx.x;
  // XCD band swizzle: blocks with the same (bx&7) share an XCD; give each
  // XCD a contiguous 64-row band so I re-reads stay in its 4MB L2.
  const int h = ((bx & 7) << 6) + (bx >> 3);
  const int b = blockIdx.y;
  const int f = threadIdx.x * 4;
  const float* Ib = I + (size_t)b * HH * RSTR;
  const float* Tb = T + (size_t)b * NBLK * RSTR;
  const float4 xv = *(const float4*)(x + ((size_t)b * HH + h) * ROWF + f);
  float* ob = out + ((size_t)b * 3 * HH + h) * ROWF + f;

  int wj[4];
#pragma unroll
  for (int j = 0; j < 4; ++j) wj[j] = (f + j) / 3;

  const int RADv[3] = {3, 7, 15};
#pragma unroll
  for (int s = 0; s < 3; ++s) {
    const int r = RADv[s], r3 = 3 * r;
    const int rt = min(h + r, HH - 1);
    const int rb = h - r;
    float4 hs = make_float4(0.f, 0.f, 0.f, 0.f);
    acc_hsum<false>(Ib + (size_t)rt * RSTR + PADL + f, r3, hs);
    const int bt = rt >> 5;
    if (rb >= 1) {
      acc_hsum<true>(Ib + (size_t)(rb - 1) * RSTR + PADL + f, r3, hs);
      for (int k = (rb - 1) >> 5; k < bt; ++k)      // <=1 iter for HBLK=32
        acc_hsum<false>(Tb + (size_t)k * RSTR + PADL + f, r3, hs);
    } else {
      for (int k = 0; k < bt; ++k)                  // empty for HBLK=32
        acc_hsum<false>(Tb + (size_t)k * RSTR + PADL + f, r3, hs);
    }
    const int rowcnt = rt - max(rb, 0) + 1;
    const float invrow = __builtin_amdgcn_rcpf((float)rowcnt);
    float hv[4] = {hs.x, hs.y, hs.z, hs.w};
    float xs[4] = {xv.x, xv.y, xv.z, xv.w};
    float rv[4];
#pragma unroll
    for (int j = 0; j < 4; ++j) {
      int cc = min(wj[j] + r, WW - 1) - max(wj[j] - r, 0) + 1;
      rv[j] = hv[j] * (invrow * __builtin_amdgcn_rcpf((float)cc)) - xs[j];
    }
    *(float4*)(ob + (size_t)s * HH * ROWF) =
        make_float4(rv[0], rv[1], rv[2], rv[3]);
  }
}

// ================= fallback path (round-3, proven passing) ==============
__global__ __launch_bounds__(256) void row_prefix_kernel(
    const float* __restrict__ x, float* __restrict__ P) {
  const int wave = threadIdx.x >> 6;
  const int lane = threadIdx.x & 63;
  const int row = blockIdx.x * 4 + wave;
  const size_t base = (size_t)row * ROWF + (size_t)lane * 24;
  float v[24];
  const float4* s4 = reinterpret_cast<const float4*>(x + base);
#pragma unroll
  for (int i = 0; i < 6; ++i) {
    float4 t = s4[i];
    v[i*4] = t.x; v[i*4+1] = t.y; v[i*4+2] = t.z; v[i*4+3] = t.w;
  }
  float tot[3];
#pragma unroll
  for (int c = 0; c < 3; ++c) {
    float run = 0.f;
#pragma unroll
    for (int wl = 0; wl < 8; ++wl) { run += v[wl*3+c]; v[wl*3+c] = run; }
    tot[c] = run;
  }
#pragma unroll
  for (int c = 0; c < 3; ++c) {
    float t = tot[c];
#pragma unroll
    for (int d = 1; d < 64; d <<= 1) {
      float n = __shfl_up(t, d, 64);
      if (lane >= d) t += n;
    }
    float off = t - tot[c];
#pragma unroll
    for (int wl = 0; wl < 8; ++wl) v[wl*3+c] += off;
  }
  float4* d4 = reinterpret_cast<float4*>(P + base);
#pragma unroll
  for (int i = 0; i < 6; ++i)
    d4[i] = make_float4(v[i*4], v[i*4+1], v[i*4+2], v[i*4+3]);
}

__global__ __launch_bounds__(256) void window_dev_kernel(
    const float* __restrict__ x, const float* __restrict__ P,
    float* __restrict__ out) {
  const int RAD[3] = {3, 7, 15};
  const int flat = blockIdx.x * 256 + threadIdx.x;
  const int w = flat / 3;
  const int c = flat - w * 3;
  const int b = blockIdx.z;
  const int h0 = blockIdx.y * 64;
  const float* Pb = P + (size_t)b * HH * ROWF;
  const float* xb = x + (size_t)b * HH * ROWF;
  float* ob = out + (size_t)b * 3 * HH * ROWF;
  int ihi[3], ilo[3];
  float mlo[3], invcol[3];
#pragma unroll
  for (int s = 0; s < 3; ++s) {
    const int r = RAD[s];
    int lo = w - r; if (lo < 0) lo = 0;
    int hi = w + r; if (hi > WW - 1) hi = WW - 1;
    invcol[s] = __builtin_amdgcn_rcpf((float)(hi - lo + 1));
    ihi[s] = hi * 3 + c;
    ilo[s] = (lo > 0) ? ((lo - 1) * 3 + c) : c;
    mlo[s] = (lo > 0) ? 1.f : 0.f;
  }
  float S[3];
#pragma unroll
  for (int s = 0; s < 3; ++s) {
    const int r = RAD[s];
    int r0 = h0 - r; if (r0 < 0) r0 = 0;
    int r1 = h0 + r; if (r1 > HH - 1) r1 = HH - 1;
    float acc = 0.f;
    for (int hh = r0; hh <= r1; ++hh) {
      const float* Pr = Pb + (size_t)hh * ROWF;
      acc += Pr[ihi[s]] - mlo[s] * Pr[ilo[s]];
    }
    S[s] = acc;
  }
  for (int h = h0; h < h0 + 64; ++h) {
    const float xvv = xb[(size_t)h * ROWF + flat];
    float invrow[3];
#pragma unroll
    for (int s = 0; s < 3; ++s) {
      const int r = RAD[s];
      int rt = h + r; if (rt > HH - 1) rt = HH - 1;
      int rbv = h - r; if (rbv < 0) rbv = 0;
      invrow[s] = __builtin_amdgcn_rcpf((float)(rt - rbv + 1));
    }
#pragma unroll
    for (int s = 0; s < 3; ++s) {
      const int r = RAD[s];
      const float avg = S[s] * (invrow[s] * invcol[s]);
      ob[((size_t)s * HH + h) * ROWF + flat] = avg - xvv;
      const int add = h + 1 + r;
      const int rem = h - r;
      float d = 0.f;
      if (add < HH) {
        const float* Pr = Pb + (size_t)add * ROWF;
        d += Pr[ihi[s]] - mlo[s] * Pr[ilo[s]];
      }
      if (rem >= 0) {
        const float* Pr = Pb + (size_t)rem * ROWF;
        d -= Pr[ihi[s]] - mlo[s] * Pr[ilo[s]];
      }
      S[s] += d;
    }
  }
}

// ========================================================================
extern "C" void kernel_launch(void* const* d_in, const int* in_sizes, int n_in,
                              void* d_out, int out_size, void* d_ws, size_t ws_size,
                              hipStream_t stream) {
  const float* x = (const float*)d_in[0];
  float* outp = (float*)d_out;
  const size_t need = (I_FLOATS + T_FLOATS) * sizeof(float);

  if (ws_size >= need) {
    float* I = (float*)d_ws;
    float* T = I + I_FLOATS;
    dim3 g1(NBLK, NB);                 // (16,16): 256 blocks x 4 waves
    fused_prefix<<<g1, 256, 0, stream>>>(x, I, T);
    dim3 g2(HH, NB);
    win_dev_ii<<<g2, 384, 0, stream>>>(x, I, T, outp);
  } else {
    float* P = (float*)d_ws;
    row_prefix_kernel<<<NROWS / 4, 256, 0, stream>>>(x, P);
    dim3 grid(ROWF / 256, HH / 64, 16);
    window_dev_kernel<<<grid, 256, 0, stream>>>(x, P, outp);
  }
}

// Round 8
// 230.543 us; speedup vs baseline: 1.4365x; 1.0194x over previous
//
#include <hip/hip_runtime.h>
#include <hip/hip_bf16.h>

// x (16,512,512,3) fp32 NHWC -> out (16,3,512,512,3):
//   out[b][s][h][w][c] = avgpool_same_{k_s}(x) - x,  k in {7,15,31},
// exclude-padding averages (count = rowcnt(h)*colcnt(w)).
//
// K1 (fused): row prefix + 16-row-block vertical prefix + block totals T.
// K2: window = I[rt] - I[rb-1] + T fixups; x derived from I (no x read);
//     XCD-banded h mapping for L2 reuse; nontemporal out stores.

#define HH 512
#define WW 512
#define ROWF 1536               // data floats per row (512*3)
#define NROWS (16 * HH)
#define PADL 48                 // 16 px * 3 c
#define PADR 48
#define RSTR (PADL + ROWF + PADR)  // 1632 floats
#define HBLK 16
#define NBLK (HH / HBLK)        // 32
#define NB 16
#define RPW (HBLK / 4)          // rows per wave = 4

typedef float nfloat4 __attribute__((ext_vector_type(4)));  // native vec for nt-store

static const size_t I_FLOATS = (size_t)NB * HH * RSTR;     // 13,369,344
static const size_t T_FLOATS = (size_t)NB * NBLK * RSTR;   // 835,584

// ---------------- K1: fused row prefix + vertical partial prefix --------
// 256 threads = 4 waves; block owns 16 rows of one image. Wave w handles
// rows [w*4, w*4+4): row scan + vertical running acc in regs. Cross-wave
// offsets via LDS; waves 1-3 re-read their rows (L2-hot) and add offsets;
// wave 0 writes T.
__global__ __launch_bounds__(256) void fused_prefix(
    const float* __restrict__ x, float* __restrict__ I, float* __restrict__ T) {
  __shared__ float wtot[4][64][25];   // stride 25 -> bank-conflict-free
  const int wv = threadIdx.x >> 6;
  const int lane = threadIdx.x & 63;
  const int blk = blockIdx.x;         // 0..NBLK-1
  const int b = blockIdx.y;           // 0..NB-1
  const int row0 = b * HH + blk * HBLK + wv * RPW;

  float acc[24];
#pragma unroll
  for (int j = 0; j < 24; ++j) acc[j] = 0.f;

  for (int rr = 0; rr < RPW; ++rr) {
    const int row = row0 + rr;
    const float4* s4 = (const float4*)(x + (size_t)row * ROWF + lane * 24);
    float v[24];
#pragma unroll
    for (int i = 0; i < 6; ++i) {
      float4 t = s4[i];
      v[4*i] = t.x; v[4*i+1] = t.y; v[4*i+2] = t.z; v[4*i+3] = t.w;
    }
    float tot[3];
#pragma unroll
    for (int c = 0; c < 3; ++c) {
      float run = 0.f;
#pragma unroll
      for (int wl = 0; wl < 8; ++wl) { run += v[wl*3+c]; v[wl*3+c] = run; }
      tot[c] = run;
    }
#pragma unroll
    for (int c = 0; c < 3; ++c) {
      float t = tot[c];
#pragma unroll
      for (int d = 1; d < 64; d <<= 1) {
        float n = __shfl_up(t, d, 64);
        if (lane >= d) t += n;
      }
      float off = t - tot[c];
#pragma unroll
      for (int wl = 0; wl < 8; ++wl) v[wl*3+c] += off;
    }
#pragma unroll
    for (int j = 0; j < 24; ++j) acc[j] += v[j];

    float rp0 = __shfl(acc[21], 63, 64);
    float rp1 = __shfl(acc[22], 63, 64);
    float rp2 = __shfl(acc[23], 63, 64);

    float* dst = I + (size_t)row * RSTR;
    float4* d4 = (float4*)(dst + PADL + lane * 24);
#pragma unroll
    for (int i = 0; i < 6; ++i)
      d4[i] = make_float4(acc[4*i], acc[4*i+1], acc[4*i+2], acc[4*i+3]);
    if (lane < 12) {
      ((float4*)dst)[lane] = make_float4(0.f, 0.f, 0.f, 0.f);
      float rp[3] = {rp0, rp1, rp2};
      float p[4];
#pragma unroll
      for (int j = 0; j < 4; ++j) p[j] = rp[(lane * 4 + j) % 3];
      ((float4*)(dst + PADL + ROWF))[lane] = make_float4(p[0], p[1], p[2], p[3]);
    }
  }

#pragma unroll
  for (int j = 0; j < 24; ++j) wtot[wv][lane][j] = acc[j];
  __syncthreads();

  if (wv == 0) {
    float tt[24];
#pragma unroll
    for (int j = 0; j < 24; ++j)
      tt[j] = wtot[0][lane][j] + wtot[1][lane][j] + wtot[2][lane][j] + wtot[3][lane][j];
    float* trow = T + ((size_t)b * NBLK + blk) * RSTR;
    float4* t4 = (float4*)(trow + PADL + lane * 24);
#pragma unroll
    for (int i = 0; i < 6; ++i)
      t4[i] = make_float4(tt[4*i], tt[4*i+1], tt[4*i+2], tt[4*i+3]);
    if (lane < 12) {
      ((float4*)trow)[lane] = make_float4(0.f, 0.f, 0.f, 0.f);
      float tp[3];
#pragma unroll
      for (int c = 0; c < 3; ++c)
        tp[c] = wtot[0][63][21+c] + wtot[1][63][21+c] +
                wtot[2][63][21+c] + wtot[3][63][21+c];
      float p[4];
#pragma unroll
      for (int j = 0; j < 4; ++j) p[j] = tp[(lane * 4 + j) % 3];
      ((float4*)(trow + PADL + ROWF))[lane] = make_float4(p[0], p[1], p[2], p[3]);
    }
  } else {
    float off[24];
#pragma unroll
    for (int j = 0; j < 24; ++j) {
      float o = wtot[0][lane][j];
      if (wv >= 2) o += wtot[1][lane][j];
      if (wv >= 3) o += wtot[2][lane][j];
      off[j] = o;
    }
    float offp[3];
#pragma unroll
    for (int c = 0; c < 3; ++c) {
      float o = wtot[0][63][21+c];
      if (wv >= 2) o += wtot[1][63][21+c];
      if (wv >= 3) o += wtot[2][63][21+c];
      offp[c] = o;
    }
    for (int rr = 0; rr < RPW; ++rr) {
      float* dst = I + (size_t)(row0 + rr) * RSTR;
      float4* d4 = (float4*)(dst + PADL + lane * 24);
#pragma unroll
      for (int i = 0; i < 6; ++i) {
        float4 t = d4[i];
        t.x += off[4*i]; t.y += off[4*i+1]; t.z += off[4*i+2]; t.w += off[4*i+3];
        d4[i] = t;
      }
      if (lane < 12) {
        float4* rp = ((float4*)(dst + PADL + ROWF)) + lane;
        float4 t = *rp;
        t.x += offp[(lane*4+0)%3]; t.y += offp[(lane*4+1)%3];
        t.z += offp[(lane*4+2)%3]; t.w += offp[(lane*4+3)%3];
        *rp = t;
      }
    }
  }
}

// ---------------- K2: per-(b,h) window deviations -----------------------
template <bool SUB>
__device__ __forceinline__ void acc_hsum(const float* __restrict__ Rp,
                                         int r3, float4& a) {
  float4 L = *(const float4*)(Rp + r3 - 1);
  float4 H = *(const float4*)(Rp + r3 + 3);
  float4 C = *(const float4*)(Rp - r3 - 3);
  if (!SUB) {
    a.x += L.y - C.x; a.y += L.z - C.y; a.z += L.w - C.z; a.w += H.x - C.w;
  } else {
    a.x -= L.y - C.x; a.y -= L.z - C.y; a.z -= L.w - C.z; a.w -= H.x - C.w;
  }
}

__global__ __launch_bounds__(384) void win_dev_ii(
    const float* __restrict__ I, const float* __restrict__ T,
    float* __restrict__ out) {
  const int bx = blockIdx.x;
  // XCD band swizzle: blocks with the same (bx&7) share an XCD; each XCD
  // owns a contiguous 64-row band so its I rows stay in the 4MB L2.
  const int h = ((bx & 7) << 6) + (bx >> 3);
  const int b = blockIdx.y;
  const int f = threadIdx.x * 4;
  const float* Ib = I + (size_t)b * HH * RSTR;
  const float* Tb = T + (size_t)b * NBLK * RSTR;
  float* ob = out + ((size_t)b * 3 * HH + h) * ROWF + f;

  // derive x[h][f..f+3] from I (rows h, h-1 are L2-hot):
  //   x[h] = dW(I[h]) - dW(I[h-1]),  dW(R)[j] = R[j] - R[j-3]
  const float* Rh = Ib + (size_t)h * RSTR + PADL + f;
  float4 a0 = *(const float4*)(Rh - 4);   // f-4..f-1 (pad zeros at f=0)
  float4 a1 = *(const float4*)(Rh);       // f..f+3
  float xs[4] = {a1.x - a0.y, a1.y - a0.z, a1.z - a0.w, a1.w - a1.x};
  if (h & (HBLK - 1)) {                   // h-1 in same vertical block
    const float* Rm = Rh - RSTR;
    float4 b0 = *(const float4*)(Rm - 4);
    float4 b1 = *(const float4*)(Rm);
    xs[0] -= b1.x - b0.y; xs[1] -= b1.y - b0.z;
    xs[2] -= b1.z - b0.w; xs[3] -= b1.w - b1.x;
  }

  int wj[4];
#pragma unroll
  for (int j = 0; j < 4; ++j) wj[j] = (f + j) / 3;

  const int RADv[3] = {3, 7, 15};
#pragma unroll
  for (int s = 0; s < 3; ++s) {
    const int r = RADv[s], r3 = 3 * r;
    const int rt = min(h + r, HH - 1);
    const int rb = h - r;
    float4 hs = make_float4(0.f, 0.f, 0.f, 0.f);
    acc_hsum<false>(Ib + (size_t)rt * RSTR + PADL + f, r3, hs);
    const int bt = rt >> 4;
    if (rb >= 1) {
      acc_hsum<true>(Ib + (size_t)(rb - 1) * RSTR + PADL + f, r3, hs);
      for (int k = (rb - 1) >> 4; k < bt; ++k)      // <=2 iters (HBLK=16)
        acc_hsum<false>(Tb + (size_t)k * RSTR + PADL + f, r3, hs);
    } else {
      for (int k = 0; k < bt; ++k)                  // <=1 iter
        acc_hsum<false>(Tb + (size_t)k * RSTR + PADL + f, r3, hs);
    }
    const int rowcnt = rt - max(rb, 0) + 1;
    const float invrow = __builtin_amdgcn_rcpf((float)rowcnt);
    float hv[4] = {hs.x, hs.y, hs.z, hs.w};
    float rv[4];
#pragma unroll
    for (int j = 0; j < 4; ++j) {
      int cc = min(wj[j] + r, WW - 1) - max(wj[j] - r, 0) + 1;
      rv[j] = hv[j] * (invrow * __builtin_amdgcn_rcpf((float)cc)) - xs[j];
    }
    // out is write-once: bypass L2 so I rows stay resident
    nfloat4 sv; sv.x = rv[0]; sv.y = rv[1]; sv.z = rv[2]; sv.w = rv[3];
    __builtin_nontemporal_store(sv, (nfloat4*)(ob + (size_t)s * HH * ROWF));
  }
}

// ================= fallback path (round-3, proven passing) ==============
__global__ __launch_bounds__(256) void row_prefix_kernel(
    const float* __restrict__ x, float* __restrict__ P) {
  const int wave = threadIdx.x >> 6;
  const int lane = threadIdx.x & 63;
  const int row = blockIdx.x * 4 + wave;
  const size_t base = (size_t)row * ROWF + (size_t)lane * 24;
  float v[24];
  const float4* s4 = reinterpret_cast<const float4*>(x + base);
#pragma unroll
  for (int i = 0; i < 6; ++i) {
    float4 t = s4[i];
    v[i*4] = t.x; v[i*4+1] = t.y; v[i*4+2] = t.z; v[i*4+3] = t.w;
  }
  float tot[3];
#pragma unroll
  for (int c = 0; c < 3; ++c) {
    float run = 0.f;
#pragma unroll
    for (int wl = 0; wl < 8; ++wl) { run += v[wl*3+c]; v[wl*3+c] = run; }
    tot[c] = run;
  }
#pragma unroll
  for (int c = 0; c < 3; ++c) {
    float t = tot[c];
#pragma unroll
    for (int d = 1; d < 64; d <<= 1) {
      float n = __shfl_up(t, d, 64);
      if (lane >= d) t += n;
    }
    float off = t - tot[c];
#pragma unroll
    for (int wl = 0; wl < 8; ++wl) v[wl*3+c] += off;
  }
  float4* d4 = reinterpret_cast<float4*>(P + base);
#pragma unroll
  for (int i = 0; i < 6; ++i)
    d4[i] = make_float4(v[i*4], v[i*4+1], v[i*4+2], v[i*4+3]);
}

__global__ __launch_bounds__(256) void window_dev_kernel(
    const float* __restrict__ x, const float* __restrict__ P,
    float* __restrict__ out) {
  const int RAD[3] = {3, 7, 15};
  const int flat = blockIdx.x * 256 + threadIdx.x;
  const int w = flat / 3;
  const int c = flat - w * 3;
  const int b = blockIdx.z;
  const int h0 = blockIdx.y * 64;
  const float* Pb = P + (size_t)b * HH * ROWF;
  const float* xb = x + (size_t)b * HH * ROWF;
  float* ob = out + (size_t)b * 3 * HH * ROWF;
  int ihi[3], ilo[3];
  float mlo[3], invcol[3];
#pragma unroll
  for (int s = 0; s < 3; ++s) {
    const int r = RAD[s];
    int lo = w - r; if (lo < 0) lo = 0;
    int hi = w + r; if (hi > WW - 1) hi = WW - 1;
    invcol[s] = __builtin_amdgcn_rcpf((float)(hi - lo + 1));
    ihi[s] = hi * 3 + c;
    ilo[s] = (lo > 0) ? ((lo - 1) * 3 + c) : c;
    mlo[s] = (lo > 0) ? 1.f : 0.f;
  }
  float S[3];
#pragma unroll
  for (int s = 0; s < 3; ++s) {
    const int r = RAD[s];
    int r0 = h0 - r; if (r0 < 0) r0 = 0;
    int r1 = h0 + r; if (r1 > HH - 1) r1 = HH - 1;
    float acc = 0.f;
    for (int hh = r0; hh <= r1; ++hh) {
      const float* Pr = Pb + (size_t)hh * ROWF;
      acc += Pr[ihi[s]] - mlo[s] * Pr[ilo[s]];
    }
    S[s] = acc;
  }
  for (int h = h0; h < h0 + 64; ++h) {
    const float xvv = xb[(size_t)h * ROWF + flat];
    float invrow[3];
#pragma unroll
    for (int s = 0; s < 3; ++s) {
      const int r = RAD[s];
      int rt = h + r; if (rt > HH - 1) rt = HH - 1;
      int rbv = h - r; if (rbv < 0) rbv = 0;
      invrow[s] = __builtin_amdgcn_rcpf((float)(rt - rbv + 1));
    }
#pragma unroll
    for (int s = 0; s < 3; ++s) {
      const int r = RAD[s];
      const float avg = S[s] * (invrow[s] * invcol[s]);
      ob[((size_t)s * HH + h) * ROWF + flat] = avg - xvv;
      const int add = h + 1 + r;
      const int rem = h - r;
      float d = 0.f;
      if (add < HH) {
        const float* Pr = Pb + (size_t)add * ROWF;
        d += Pr[ihi[s]] - mlo[s] * Pr[ilo[s]];
      }
      if (rem >= 0) {
        const float* Pr = Pb + (size_t)rem * ROWF;
        d -= Pr[ihi[s]] - mlo[s] * Pr[ilo[s]];
      }
      S[s] += d;
    }
  }
}

// ========================================================================
extern "C" void kernel_launch(void* const* d_in, const int* in_sizes, int n_in,
                              void* d_out, int out_size, void* d_ws, size_t ws_size,
                              hipStream_t stream) {
  const float* x = (const float*)d_in[0];
  float* outp = (float*)d_out;
  const size_t need = (I_FLOATS + T_FLOATS) * sizeof(float);

  if (ws_size >= need) {
    float* I = (float*)d_ws;
    float* T = I + I_FLOATS;
    dim3 g1(NBLK, NB);                 // (32,16): 512 blocks x 4 waves
    fused_prefix<<<g1, 256, 0, stream>>>(x, I, T);
    dim3 g2(HH, NB);
    win_dev_ii<<<g2, 384, 0, stream>>>(I, T, outp);
  } else {
    float* P = (float*)d_ws;
    row_prefix_kernel<<<NROWS / 4, 256, 0, stream>>>(x, P);
    dim3 grid(ROWF / 256, HH / 64, 16);
    window_dev_kernel<<<grid, 256, 0, stream>>>(x, P, outp);
  }
}